// Round 1
// baseline (297.652 us; speedup 1.0000x reference)
//
#include <hip/hip_runtime.h>

#define CD 1024
#define NB 4096

typedef __attribute__((ext_vector_type(8))) short short8;
typedef __attribute__((ext_vector_type(4))) short short4v;
typedef __attribute__((ext_vector_type(4))) float f32x4;
typedef __attribute__((ext_vector_type(4))) int int4v;

typedef __attribute__((address_space(1))) const void gv_t;
typedef __attribute__((address_space(3))) void lv_t;
#define GLOAD16(g, l) __builtin_amdgcn_global_load_lds((gv_t*)(g), (lv_t*)(l), 16, 0, 0)

__device__ __forceinline__ short f2bf(float f) {
  unsigned u = __float_as_uint(f);
  u = (u + 0x7FFFu + ((u >> 16) & 1u)) >> 16;
  return (short)u;
}
__device__ __forceinline__ float bf2f(short s) {
  return __uint_as_float(((unsigned)(unsigned short)s) << 16);
}

// ---- x f32 -> bf16 ----
__global__ __launch_bounds__(256) void cvtx_kernel(const float* __restrict__ x,
                                                   short* __restrict__ xb) {
  int i = (blockIdx.x * 256 + threadIdx.x) * 8;
  f32x4 a = *(const f32x4*)(x + i);
  f32x4 b = *(const f32x4*)(x + i + 4);
  short8 o;
  o[0] = f2bf(a[0]); o[1] = f2bf(a[1]); o[2] = f2bf(a[2]); o[3] = f2bf(a[3]);
  o[4] = f2bf(b[0]); o[5] = f2bf(b[1]); o[6] = f2bf(b[2]); o[7] = f2bf(b[3]);
  *(short8*)(xb + i) = o;
}

// ---- dequant all 12 layers + fold LoRA:  Wb[l][o][k] = deq + sum_r B[o][r]*A[r][k] ----
__global__ __launch_bounds__(256) void deq_kernel(const int* __restrict__ q4,
                                                  const float* __restrict__ nrm,
                                                  const float* __restrict__ la,
                                                  const float* __restrict__ lb,
                                                  short* __restrict__ Wb) {
  int tidg = blockIdx.x * 256 + threadIdx.x;
  int w0 = tidg * 4;                       // int32-word index, 4 words/thread
  int l = w0 >> 19;                        // 524288 words per layer
  int wl = w0 & 524287;
  int g = wl >> 6;                         // group (64 words each)
  int j0 = wl & 63;                        // word within group (multiple of 4)
  int o = g >> 3;                          // 8 groups per output row
  int kb = ((g & 7) << 7) + (j0 << 1);     // base k, multiple of 8
  int4v q = *(const int4v*)(q4 + w0);
  float n = nrm[(l << 13) + g];
  float s = n * (2.0f / 15.0f);
  f32x4 B = *(const f32x4*)(lb + (((l << 10) + o) << 2));
  const float* A = la + (l << 12);
  float Ar[4][8];
#pragma unroll
  for (int r = 0; r < 4; ++r) {
    f32x4 u = *(const f32x4*)(A + r * CD + kb);
    f32x4 v = *(const f32x4*)(A + r * CD + kb + 4);
    Ar[r][0] = u[0]; Ar[r][1] = u[1]; Ar[r][2] = u[2]; Ar[r][3] = u[3];
    Ar[r][4] = v[0]; Ar[r][5] = v[1]; Ar[r][6] = v[2]; Ar[r][7] = v[3];
  }
  short8 outv;
#pragma unroll
  for (int p = 0; p < 8; ++p) {
    int qw = q[p >> 1];
    int nib = (qw >> ((p & 1) << 2)) & 15;
    float wv = (float)nib * s - n;
    wv += B[0] * Ar[0][p] + B[1] * Ar[1][p] + B[2] * Ar[2][p] + B[3] * Ar[3][p];
    outv[p] = f2bf(wv);
  }
  *(short8*)(Wb + (l << 20) + (o << 10) + kb) = outv;
}

// ---- GEMM: out[M,O] = Act[M,K] @ W[O,K]^T, bf16 in, f32 acc ----
// EPI: 0 = relu->bf16, 2 = +resid->bf16, 3 = +resid->f32
template <int EPI>
__global__ __launch_bounds__(256) void qgemm(const short* __restrict__ Act,
                                             const short* __restrict__ W,
                                             const short* __restrict__ Res,
                                             void* __restrict__ Out) {
  __shared__ __align__(16) short lds[2][2][128 * 64];
  const int tid = threadIdx.x;
  const int lane = tid & 63;
  const int wid = tid >> 6;
  const int wr = wid >> 1, wc = wid & 1;
  const int m0 = blockIdx.x * 128;
  const int o0 = blockIdx.y * 128;

  // staging: LDS linear (gload_lds), global source pre-swizzled: chunk ^= row&7
  const int srow = (wid << 5) + (lane >> 3);          // tile row for i=0
  const int gch = (lane & 7) ^ (lane >> 3);           // swizzled 16B-chunk index
  const short* aptr[4];
  const short* bptr[4];
#pragma unroll
  for (int i = 0; i < 4; ++i) {
    int r = srow + i * 8;
    aptr[i] = Act + (long)(m0 + r) * CD + (gch << 3);
    bptr[i] = W + (long)(o0 + r) * CD + (gch << 3);
  }

  auto stage = [&](int t, int buf) {
    const int koff = t << 6;
#pragma unroll
    for (int i = 0; i < 4; ++i) {
      GLOAD16(aptr[i] + koff, &lds[buf][0][((wid << 5) + (i << 3)) << 6]);
      GLOAD16(bptr[i] + koff, &lds[buf][1][((wid << 5) + (i << 3)) << 6]);
    }
  };

  f32x4 acc[4][4] = {};
  const int frow = lane & 15;
  const int fch = lane >> 4;
  const int fsw = lane & 7;

  stage(0, 0);
  for (int t = 0; t < 16; ++t) {
    __syncthreads();                       // drains vmcnt(0): buf[t&1] ready
    if (t < 15) stage(t + 1, (t + 1) & 1); // prefetch next tile into other buf
    const short* La = lds[t & 1][0];
    const short* Lb = lds[t & 1][1];
#pragma unroll
    for (int kk = 0; kk < 2; ++kk) {
      short8 af[4], bfr[4];
#pragma unroll
      for (int m = 0; m < 4; ++m) {
        int row = (wr << 6) + (m << 4) + frow;
        int ch = ((kk << 2) + fch) ^ fsw;
        af[m] = *(const short8*)(La + (row << 6) + (ch << 3));
      }
#pragma unroll
      for (int nn = 0; nn < 4; ++nn) {
        int row = (wc << 6) + (nn << 4) + frow;
        int ch = ((kk << 2) + fch) ^ fsw;
        bfr[nn] = *(const short8*)(Lb + (row << 6) + (ch << 3));
      }
#pragma unroll
      for (int m = 0; m < 4; ++m)
#pragma unroll
        for (int nn = 0; nn < 4; ++nn)
          acc[m][nn] = __builtin_amdgcn_mfma_f32_16x16x32_bf16(af[m], bfr[nn], acc[m][nn], 0, 0, 0);
    }
  }

  // epilogue: D mapping col=lane&15, row=(lane>>4)*4+reg
  const int colb = o0 + (wc << 6) + frow;
  const int rowb = m0 + (wr << 6) + (fch << 2);
#pragma unroll
  for (int m = 0; m < 4; ++m) {
#pragma unroll
    for (int nn = 0; nn < 4; ++nn) {
#pragma unroll
      for (int r = 0; r < 4; ++r) {
        int row = rowb + (m << 4) + r;
        int col = colb + (nn << 4);
        float v = acc[m][nn][r];
        if (EPI == 0) {
          v = fmaxf(v, 0.0f);
          ((short*)Out)[(long)row * CD + col] = f2bf(v);
        } else if (EPI == 2) {
          v += bf2f(Res[(long)row * CD + col]);
          ((short*)Out)[(long)row * CD + col] = f2bf(v);
        } else {
          v += bf2f(Res[(long)row * CD + col]);
          ((float*)Out)[(long)row * CD + col] = v;
        }
      }
    }
  }
}

// ---- LayerNorm over rows of 1024 bf16 ----
__global__ __launch_bounds__(256) void ln_kernel(const short* __restrict__ in,
                                                 short* __restrict__ out,
                                                 const float* __restrict__ g,
                                                 const float* __restrict__ b) {
  __shared__ float rs_[4], rq_[4];
  int row = blockIdx.x, tid = threadIdx.x;
  int k = tid * 4;
  short4v v = *(const short4v*)(in + (long)row * CD + k);
  float f0 = bf2f(v[0]), f1 = bf2f(v[1]), f2 = bf2f(v[2]), f3 = bf2f(v[3]);
  float s = f0 + f1 + f2 + f3;
  float q = f0 * f0 + f1 * f1 + f2 * f2 + f3 * f3;
#pragma unroll
  for (int off = 1; off < 64; off <<= 1) {
    s += __shfl_xor(s, off);
    q += __shfl_xor(q, off);
  }
  if ((tid & 63) == 0) { rs_[tid >> 6] = s; rq_[tid >> 6] = q; }
  __syncthreads();
  s = rs_[0] + rs_[1] + rs_[2] + rs_[3];
  q = rq_[0] + rq_[1] + rq_[2] + rq_[3];
  float mu = s * (1.0f / 1024.0f);
  float var = q * (1.0f / 1024.0f) - mu * mu;
  float rstd = rsqrtf(var + 1e-5f);
  short4v o;
  o[0] = f2bf((f0 - mu) * rstd * g[k] + b[k]);
  o[1] = f2bf((f1 - mu) * rstd * g[k + 1] + b[k + 1]);
  o[2] = f2bf((f2 - mu) * rstd * g[k + 2] + b[k + 2]);
  o[3] = f2bf((f3 - mu) * rstd * g[k + 3] + b[k + 3]);
  *(short4v*)(out + (long)row * CD + k) = o;
}

extern "C" void kernel_launch(void* const* d_in, const int* in_sizes, int n_in,
                              void* d_out, int out_size, void* d_ws, size_t ws_size,
                              hipStream_t stream) {
  const float* x = (const float*)d_in[0];
  const int* q4 = (const int*)d_in[1];
  const float* nrm = (const float*)d_in[2];
  const float* la = (const float*)d_in[3];
  const float* lb = (const float*)d_in[4];
  const float* lng = (const float*)d_in[5];
  const float* lnb = (const float*)d_in[6];

  short* Wb = (short*)d_ws;                             // 24 MB: 12 x [1024][1024] bf16
  short* buf0 = (short*)((char*)d_ws + (24u << 20));    // 8 MB
  short* buf1 = buf0 + (long)NB * CD;                   // 8 MB
  short* buf2 = (short*)d_out;                          // d_out as bf16 scratch (lower 8 MB)
  short* buf3 = buf2 + (long)NB * CD;                   // d_out upper 8 MB
  float* outf = (float*)d_out;

  cvtx_kernel<<<dim3(2048), dim3(256), 0, stream>>>(x, buf0);
  deq_kernel<<<dim3(6144), dim3(256), 0, stream>>>(q4, nrm, la, lb, Wb);

  dim3 gg(32, 8), bb(256);
  auto Wl = [&](int l) { return Wb + ((long)l << 20); };

  // block 1 (input xb = buf0, resid buf0)
  qgemm<0><<<gg, bb, 0, stream>>>(buf0, Wl(0), nullptr, buf1);
  qgemm<0><<<gg, bb, 0, stream>>>(buf1, Wl(1), nullptr, buf2);
  qgemm<2><<<gg, bb, 0, stream>>>(buf2, Wl(2), buf0, buf3);
  ln_kernel<<<dim3(4096), dim3(256), 0, stream>>>(buf3, buf0, lng, lnb);
  // block 2 (input/resid buf0)
  qgemm<0><<<gg, bb, 0, stream>>>(buf0, Wl(3), nullptr, buf1);
  qgemm<0><<<gg, bb, 0, stream>>>(buf1, Wl(4), nullptr, buf2);
  qgemm<2><<<gg, bb, 0, stream>>>(buf2, Wl(5), buf0, buf3);
  // block 3 (input/resid buf3)
  qgemm<0><<<gg, bb, 0, stream>>>(buf3, Wl(6), nullptr, buf1);
  qgemm<0><<<gg, bb, 0, stream>>>(buf1, Wl(7), nullptr, buf2);
  qgemm<2><<<gg, bb, 0, stream>>>(buf2, Wl(8), buf3, buf0);
  ln_kernel<<<dim3(4096), dim3(256), 0, stream>>>(buf0, buf1, lng + CD, lnb + CD);
  // block 4 (input/resid buf1), final layer writes f32 to d_out
  qgemm<0><<<gg, bb, 0, stream>>>(buf1, Wl(9), nullptr, buf2);
  qgemm<0><<<gg, bb, 0, stream>>>(buf2, Wl(10), nullptr, buf0);
  qgemm<3><<<gg, bb, 0, stream>>>(buf0, Wl(11), buf1, (void*)outf);
}